// Round 3
// baseline (454.042 us; speedup 1.0000x reference)
//
#include <hip/hip_runtime.h>

// SelfAttentionLayer: B=8, N=2048, D=1024, fp32 in/out.
// R10: per-stage kernel routing from measured bests.
//  - gemm256 (R9): 256x256 tile, BK=64, 1 WG/CU, 4-phase interleave.
//    Used for QKV (mode 3) and PV (mode 2) - measured ~105 us each there.
//  - gemm128 (R7): 128x256 tile, BK=32, 3-stage depth-2 glds pipeline,
//    72 KB LDS -> 2 WG/CU. Used for S=QK^T only (measured 128 us vs 150-160
//    under the 256-kernel: S's 512-WG grid = 2 lockstep rounds with nk=16
//    exposes the 1-WG/CU barrier serialization; 2 WG/CU hides it).

typedef _Float16 f16;
typedef _Float16 f16x4 __attribute__((ext_vector_type(4)));
typedef _Float16 f16x8 __attribute__((ext_vector_type(8)));
typedef float f32x4 __attribute__((ext_vector_type(4)));

#define Nn_ 2048
#define Dd 1024

typedef const __attribute__((address_space(1))) void gvoid;
typedef __attribute__((address_space(3))) void lvoid;

__device__ __forceinline__ void glds16(const void* g, void* l) {
    __builtin_amdgcn_global_load_lds((gvoid*)g, (lvoid*)l, 16, 0, 0);
}
#define BARRIER()  asm volatile("s_barrier" ::: "memory")
#define LGKM0()    asm volatile("s_waitcnt lgkmcnt(0)" ::: "memory")
#define VM6()      asm volatile("s_waitcnt vmcnt(6)" ::: "memory")
#define VM0()      asm volatile("s_waitcnt vmcnt(0)" ::: "memory")
#define PRIO1()    __builtin_amdgcn_s_setprio(1)
#define PRIO0()    __builtin_amdgcn_s_setprio(0)
#define MFMA(a, b, c) __builtin_amdgcn_mfma_f32_16x16x32_f16((a), (b), (c), 0, 0, 0)

__device__ __forceinline__ void bar_vm3() {
    asm volatile("s_waitcnt vmcnt(3)\n\ts_barrier" ::: "memory");
}
__device__ __forceinline__ void bar_vm0() {
    asm volatile("s_waitcnt vmcnt(0)\n\ts_barrier" ::: "memory");
}

// ---------------- fp32 -> fp16 convert ----------------
__global__ void cvt_kernel(const float4* __restrict__ in, f16x4* __restrict__ out, int n4) {
    int i = blockIdx.x * 256 + threadIdx.x;
    if (i >= n4) return;
    float4 f = in[i];
    f16x4 h;
    h.x = (_Float16)f.x; h.y = (_Float16)f.y; h.z = (_Float16)f.z; h.w = (_Float16)f.w;
    out[i] = h;
}

// ---------------- bias concat: bqkv[3072] = [bq|bk|bv] ----------------
__global__ void concat_bias(const float* __restrict__ bq, const float* __restrict__ bk,
                            const float* __restrict__ bv, float* __restrict__ o) {
    int i = blockIdx.x * 256 + threadIdx.x;
    if (i >= 3072) return;
    o[i] = (i < 1024) ? bq[i] : (i < 2048 ? bk[i - 1024] : bv[i - 2048]);
}

// ============ gemm128 (R7): 128m x 256n, BK=32, 3-stage, 2 WG/CU ============
// C[m][n] = sum_k A[m][k] * Bm[n][k]; fp32 out row-major (mode-2 only).
__global__ __launch_bounds__(512) void gemm128(
    const f16* __restrict__ A, const f16* __restrict__ Bm,
    float* __restrict__ Cout,
    int K, int lda, int ldb, int ldc,
    long aStride, long bStride, long cStride)
{
    __shared__ f16 sm[36864];   // 72KB: three 24KB stages
    const int tid = threadIdx.x;
    const int lane = tid & 63, wid = tid >> 6;
    const int quad = lane >> 4, l16 = lane & 15;
    const int wm = (wid & 1) * 64;        // 2 m-positions
    const int wn = (wid >> 1) * 64;       // 4 n-positions
    const long m0 = (long)blockIdx.x * 128, n0 = (long)blockIdx.y * 256;
    const int bz = blockIdx.z;
    A += (long)bz * aStride;
    Bm += (long)bz * bStride;

    const int la = tid, lb0 = tid, lb1 = tid + 512;
    const long arow = m0 + (la >> 2);
    const long brow0 = n0 + (lb0 >> 2), brow1 = n0 + (lb1 >> 2);
    const int colA  = ((la & 3) ^ ((la >> 3) & 3)) * 8;
    const int colB0 = ((lb0 & 3) ^ ((lb0 >> 3) & 3)) * 8;
    const int colB1 = ((lb1 & 3) ^ ((lb1 >> 3) & 3)) * 8;

    const f16* pa  = A + arow * lda + colA;
    const f16* pb0 = Bm + brow0 * ldb + colB0;
    const f16* pb1 = Bm + brow1 * ldb + colB1;

    const int fo = (quad ^ ((l16 >> 1) & 3)) * 8;   // fragment chunk offset

    f32x4 acc[4][4];
#pragma unroll
    for (int i = 0; i < 4; i++)
#pragma unroll
        for (int j = 0; j < 4; j++) acc[i][j] = 0.0f;

    const int nk = K >> 5;
    // prologue: tiles 0,1 -> stages 0,1  (stage stride 12288 f16; Bs at +4096)
    glds16(pa, sm + la * 8);
    glds16(pb0, sm + 4096 + lb0 * 8);
    glds16(pb1, sm + 4096 + lb1 * 8);
    if (nk > 1) {
        glds16(pa + 32, sm + 12288 + la * 8);
        glds16(pb0 + 32, sm + 16384 + lb0 * 8);
        glds16(pb1 + 32, sm + 16384 + lb1 * 8);
    }

    int cur = 0;
    for (int it = 0; it < nk; ++it) {
        if (it + 1 < nk) bar_vm3(); else bar_vm0();
        if (it + 2 < nk) {
            f16* dst = sm + ((cur >= 1) ? (cur - 1) : 2) * 12288;  // (cur+2)%3
            const int ko = (it + 2) * 32;
            glds16(pa + ko, dst + la * 8);
            glds16(pb0 + ko, dst + 4096 + lb0 * 8);
            glds16(pb1 + ko, dst + 4096 + lb1 * 8);
        }
        const f16* As = sm + cur * 12288;
        const f16* Bs = As + 4096;
        f16x8 af[4], bf[4];
#pragma unroll
        for (int rt = 0; rt < 4; rt++)
            af[rt] = *(const f16x8*)(As + (wm + rt * 16 + l16) * 32 + fo);
#pragma unroll
        for (int ct = 0; ct < 4; ct++)
            bf[ct] = *(const f16x8*)(Bs + (wn + ct * 16 + l16) * 32 + fo);
#pragma unroll
        for (int rt = 0; rt < 4; rt++)
#pragma unroll
            for (int ct = 0; ct < 4; ct++)
                acc[rt][ct] = MFMA(af[rt], bf[ct], acc[rt][ct]);
        cur = (cur == 2) ? 0 : cur + 1;
    }

    float* O = Cout + (long)bz * cStride;
#pragma unroll
    for (int ct = 0; ct < 4; ct++) {
        long n = n0 + wn + ct * 16 + l16;
#pragma unroll
        for (int rt = 0; rt < 4; rt++) {
            long mb = m0 + wm + rt * 16 + quad * 4;
#pragma unroll
            for (int r = 0; r < 4; r++)
                O[(mb + r) * ldc + n] = acc[rt][ct][r];
        }
    }
}

// ============ gemm256 (R9): 256m x 256n, BK=64, 4-phase, 1 WG/CU ============
// mode 2: fp32 out row-major, no bias       (PV -> d_out)
// mode 3: merged QKV (N=3072, 12 n-tiles): by<4 -> qh, by<8 -> kh,
//         else vT[b][e][tok] via LDS transpose (coalesced stores).
__global__ __launch_bounds__(512) void gemm256(
    const f16* __restrict__ A, const f16* __restrict__ Bm,
    const float* __restrict__ bias, void* __restrict__ Cout,
    f16* __restrict__ qh, f16* __restrict__ kh, f16* __restrict__ vT,
    int K, int lda, int ldb, int ldc, int mode,
    long aStride, long bStride, long cStride)
{
    __shared__ f16 sm[65536];   // 128 KiB: two 64 KiB stages
    const int tid = threadIdx.x;
    const int lane = tid & 63, wid = tid >> 6;
    const int quad = lane >> 4, l16 = lane & 15;
    const int wm = wid & 1;          // 2 m-positions (128 rows each)
    const int wn = wid >> 1;         // 4 n-positions (64 cols each)
    const long m0 = (long)blockIdx.x * 256, n0 = (long)blockIdx.y * 256;
    A += (long)blockIdx.z * aStride;
    Bm += (long)blockIdx.z * bStride;

    const int lr = tid >> 3;
    const int sc8 = ((tid & 7) ^ (lr & 7)) * 8;
    const f16* pa = A + (m0 + lr) * (long)lda + sc8;
    const f16* pb = Bm + (n0 + lr) * (long)ldb + sc8;
    const long a64 = 64L * lda, b64 = 64L * ldb;

    const int aRow = (wm * 128 + l16) * 64;
    const int bRow = (wn * 64 + l16) * 64;
    const int co0 = (quad ^ (l16 & 7)) * 8;          // k-half 0
    const int co1 = ((quad + 4) ^ (l16 & 7)) * 8;    // k-half 1

    f32x4 acc[8][4];
#pragma unroll
    for (int i = 0; i < 8; i++)
#pragma unroll
        for (int j = 0; j < 4; j++) acc[i][j] = 0.0f;

    const int nk = K >> 6;

#pragma unroll
    for (int q = 0; q < 4; ++q) glds16(pa + q * a64, sm + tid * 8 + q * 4096);
#pragma unroll
    for (int q = 0; q < 4; ++q) glds16(pb + q * b64, sm + 16384 + tid * 8 + q * 4096);
    if (nk > 1) {
#pragma unroll
        for (int q = 0; q < 4; ++q)
            glds16(pa + q * a64 + 64, sm + 32768 + tid * 8 + q * 4096);
#pragma unroll
        for (int q = 0; q < 4; ++q)
            glds16(pb + q * b64 + 64, sm + 49152 + tid * 8 + q * 4096);
        VM6();
    } else {
        VM0();
    }
    BARRIER();

    f16x8 af0[2][4], af1[2][4], bf0[2][2], bf1[2][2];
    {
        const f16* As = sm;
        const f16* Bs = sm + 16384;
#pragma unroll
        for (int i = 0; i < 4; ++i) {
            af0[0][i] = *(const f16x8*)(As + aRow + i * 1024 + co0);
            af0[1][i] = *(const f16x8*)(As + aRow + i * 1024 + co1);
        }
#pragma unroll
        for (int j = 0; j < 2; ++j) {
            bf0[0][j] = *(const f16x8*)(Bs + bRow + j * 1024 + co0);
            bf0[1][j] = *(const f16x8*)(Bs + bRow + j * 1024 + co1);
        }
    }
    LGKM0();

    int bo = 0;
    for (int t = 0; t < nk; ++t) {
        const f16* As = sm + bo;
        const f16* Bs = As + 16384;
        const f16* An = sm + (bo ^ 32768);
        const f16* Bn = An + 16384;
        const long kt2 = (long)(t + 2) * 64;
        const bool st = (t + 2) < nk;

        // ---- ph0: MFMA q0 (af0,bf0) | read bf1 | stage A q0,q2 (t+2)
        BARRIER();
#pragma unroll
        for (int j = 0; j < 2; ++j) {
            bf1[0][j] = *(const f16x8*)(Bs + bRow + 2048 + j * 1024 + co0);
            bf1[1][j] = *(const f16x8*)(Bs + bRow + 2048 + j * 1024 + co1);
        }
        if (st) {
            glds16(pa + 0 * a64 + kt2, sm + bo + tid * 8);
            glds16(pa + 2 * a64 + kt2, sm + bo + tid * 8 + 2 * 4096);
        }
        PRIO1();
#pragma unroll
        for (int i = 0; i < 4; ++i)
#pragma unroll
            for (int j = 0; j < 2; ++j) {
                acc[i][j] = MFMA(af0[0][i], bf0[0][j], acc[i][j]);
                acc[i][j] = MFMA(af0[1][i], bf0[1][j], acc[i][j]);
            }
        PRIO0(); LGKM0();

        // ---- ph1: MFMA q1 (af0,bf1) | read af1 | stage B q0,q1 (t+2)
        BARRIER();
#pragma unroll
        for (int i = 0; i < 4; ++i) {
            af1[0][i] = *(const f16x8*)(As + aRow + 4096 + i * 1024 + co0);
            af1[1][i] = *(const f16x8*)(As + aRow + 4096 + i * 1024 + co1);
        }
        if (st) {
            glds16(pb + 0 * b64 + kt2, sm + bo + 16384 + tid * 8);
            glds16(pb + 1 * b64 + kt2, sm + bo + 16384 + tid * 8 + 4096);
        }
        PRIO1();
#pragma unroll
        for (int i = 0; i < 4; ++i)
#pragma unroll
            for (int j = 0; j < 2; ++j) {
                acc[i][2 + j] = MFMA(af0[0][i], bf1[0][j], acc[i][2 + j]);
                acc[i][2 + j] = MFMA(af0[1][i], bf1[1][j], acc[i][2 + j]);
            }
        PRIO0(); LGKM0();

        // ---- ph2: MFMA q2 (af1,bf0) | stage B q2,q3 (t+2) | vmcnt
        BARRIER();
        if (st) {
            glds16(pb + 2 * b64 + kt2, sm + bo + 16384 + tid * 8 + 2 * 4096);
            glds16(pb + 3 * b64 + kt2, sm + bo + 16384 + tid * 8 + 3 * 4096);
        }
        PRIO1();
#pragma unroll
        for (int i = 0; i < 4; ++i)
#pragma unroll
            for (int j = 0; j < 2; ++j) {
                acc[4 + i][j] = MFMA(af1[0][i], bf0[0][j], acc[4 + i][j]);
                acc[4 + i][j] = MFMA(af1[1][i], bf0[1][j], acc[4 + i][j]);
            }
        PRIO0();
        if (st) { VM6(); } else { VM0(); }

        // ---- ph3: MFMA q3 (af1,bf1) | read next af0,bf0 | stage A q1,q3
        BARRIER();
        if (t + 1 < nk) {
#pragma unroll
            for (int i = 0; i < 4; ++i) {
                af0[0][i] = *(const f16x8*)(An + aRow + i * 1024 + co0);
                af0[1][i] = *(const f16x8*)(An + aRow + i * 1024 + co1);
            }
#pragma unroll
            for (int j = 0; j < 2; ++j) {
                bf0[0][j] = *(const f16x8*)(Bn + bRow + j * 1024 + co0);
                bf0[1][j] = *(const f16x8*)(Bn + bRow + j * 1024 + co1);
            }
        }
        if (st) {
            glds16(pa + 1 * a64 + kt2, sm + bo + tid * 8 + 4096);
            glds16(pa + 3 * a64 + kt2, sm + bo + tid * 8 + 3 * 4096);
        }
        PRIO1();
#pragma unroll
        for (int i = 0; i < 4; ++i)
#pragma unroll
            for (int j = 0; j < 2; ++j) {
                acc[4 + i][2 + j] = MFMA(af1[0][i], bf1[0][j], acc[4 + i][2 + j]);
                acc[4 + i][2 + j] = MFMA(af1[1][i], bf1[1][j], acc[4 + i][2 + j]);
            }
        PRIO0(); LGKM0();
        bo ^= 32768;
    }

    if (mode == 2) {
        float* O = (float*)Cout + (long)blockIdx.z * cStride;
#pragma unroll
        for (int ct = 0; ct < 4; ct++) {
            long n = n0 + wn * 64 + ct * 16 + l16;
#pragma unroll
            for (int rt = 0; rt < 8; rt++) {
                long mb = m0 + wm * 128 + rt * 16 + quad * 4;
#pragma unroll
                for (int r = 0; r < 4; r++)
                    O[(mb + r) * ldc + n] = acc[rt][ct][r];
            }
        }
    } else {  // mode 3: merged QKV routing (n-tile = 256 wide)
        if (blockIdx.y < 8) {
            f16* O = (blockIdx.y < 4) ? qh : kh;
#pragma unroll
            for (int ct = 0; ct < 4; ct++) {
                long n = n0 + wn * 64 + ct * 16 + l16;
                float bs = bias[n];
                long n1 = n & 1023;
#pragma unroll
                for (int rt = 0; rt < 8; rt++) {
                    long mb = m0 + wm * 128 + rt * 16 + quad * 4;
#pragma unroll
                    for (int r = 0; r < 4; r++)
                        O[(mb + r) * 1024 + n1] = (f16)(acc[rt][ct][r] + bs);
                }
            }
        } else {
            const long nb = n0 - 2048;
            const long vbase = (m0 >> 11) * (long)(Dd * Nn_) + (m0 & 2047);
#pragma unroll
            for (int g = 0; g < 4; ++g) {
                __syncthreads();
                if (wn == g) {
#pragma unroll
                    for (int ct = 0; ct < 4; ++ct) {
                        int cl = ct * 16 + l16;
                        float bs = bias[n0 + g * 64 + cl];
#pragma unroll
                        for (int rt = 0; rt < 8; rt++) {
                            int row = wm * 128 + rt * 16 + quad * 4;
#pragma unroll
                            for (int r = 0; r < 4; r++)
                                sm[cl * 264 + row + r] = (f16)(acc[rt][ct][r] + bs);
                        }
                    }
                }
                __syncthreads();
                const int rowi = tid >> 3, c = (tid & 7) * 32;
                f16* dst = vT + vbase + (nb + g * 64 + rowi) * (long)Nn_ + c;
                const f16* src = sm + rowi * 264 + c;
                *(f16x8*)(dst) = *(const f16x8*)(src);
                *(f16x8*)(dst + 8) = *(const f16x8*)(src + 8);
                *(f16x8*)(dst + 16) = *(const f16x8*)(src + 16);
                *(f16x8*)(dst + 24) = *(const f16x8*)(src + 24);
            }
        }
    }
}

// ---------------- row softmax, P fp16 written in-place over S fp32 --------
__global__ __launch_bounds__(256) void softmax_rows(float* __restrict__ S) {
    const int row = blockIdx.x * 4 + (threadIdx.x >> 6);
    const int lane = threadIdx.x & 63;
    float* Sr = S + (long)row * 2048;
    const float4* R4 = (const float4*)Sr;
    float4 t[8];
#pragma unroll
    for (int i = 0; i < 8; i++) t[i] = R4[lane + 64 * i];
    float mx = -1e30f;
#pragma unroll
    for (int i = 0; i < 8; i++)
        mx = fmaxf(mx, fmaxf(fmaxf(t[i].x, t[i].y), fmaxf(t[i].z, t[i].w)));
#pragma unroll
    for (int off = 1; off < 64; off <<= 1) mx = fmaxf(mx, __shfl_xor(mx, off, 64));
    float se = 0.0f;
#pragma unroll
    for (int i = 0; i < 8; i++) {
        t[i].x = __expf(t[i].x - mx); t[i].y = __expf(t[i].y - mx);
        t[i].z = __expf(t[i].z - mx); t[i].w = __expf(t[i].w - mx);
        se += t[i].x + t[i].y + t[i].z + t[i].w;
    }
#pragma unroll
    for (int off = 1; off < 64; off <<= 1) se += __shfl_xor(se, off, 64);
    const float li = 1.0f / se;
    f16x4* P4 = (f16x4*)Sr;
#pragma unroll
    for (int i = 0; i < 8; i++) {
        f16x4 h;
        h.x = (_Float16)(t[i].x * li); h.y = (_Float16)(t[i].y * li);
        h.z = (_Float16)(t[i].z * li); h.w = (_Float16)(t[i].w * li);
        P4[lane + 64 * i] = h;
    }
}

extern "C" void kernel_launch(void* const* d_in, const int* in_sizes, int n_in,
                              void* d_out, int out_size, void* d_ws, size_t ws_size,
                              hipStream_t stream) {
    const float* x  = (const float*)d_in[0];
    const float* Wq = (const float*)d_in[1];
    const float* bq = (const float*)d_in[2];
    const float* Wk = (const float*)d_in[3];
    const float* bk = (const float*)d_in[4];
    const float* Wv = (const float*)d_in[5];
    const float* bv = (const float*)d_in[6];

    f16* wsh = (f16*)d_ws;
    dim3 blk(512);
    const bool full = ws_size >= 234881024ULL;  // 224 MiB full-batch path

    if (full) {
        f16* qh  = wsh;
        f16* kh  = wsh + 16777216;
        f16* vT  = wsh + 33554432;
        float* S = (float*)(wsh + 50331648);        // 33554432 floats
        f16* xh  = wsh + 50331648;                  // overlaid in S (dead later)
        f16* Wh  = wsh + 67108864;
        float* bqkv = (float*)(wsh + 70254592);

        cvt_kernel<<<16384, 256, 0, stream>>>((const float4*)x, (f16x4*)xh, 4194304);
        cvt_kernel<<<1024, 256, 0, stream>>>((const float4*)Wq, (f16x4*)Wh, 262144);
        cvt_kernel<<<1024, 256, 0, stream>>>((const float4*)Wk, (f16x4*)(Wh + 1048576), 262144);
        cvt_kernel<<<1024, 256, 0, stream>>>((const float4*)Wv, (f16x4*)(Wh + 2097152), 262144);
        concat_bias<<<12, 256, 0, stream>>>(bq, bk, bv, bqkv);

        // QKV: M=16384 (64 m-tiles), N=3072 (12 n-tiles) -> gemm256
        gemm256<<<dim3(64, 12, 1), blk, 0, stream>>>(
            xh, Wh, bqkv, nullptr, qh, kh, vT,
            1024, 1024, 1024, 0, 3, 0, 0, 0);
        // S = Q K^T : per batch 16 m-tiles x 8 n-tiles -> gemm128 (2 WG/CU)
        gemm128<<<dim3(16, 8, 8), blk, 0, stream>>>(
            qh, kh, S,
            1024, 1024, 1024, 2048,
            (long)Nn_ * Dd, (long)Nn_ * Dd, (long)Nn_ * Nn_);
        softmax_rows<<<4096, 256, 0, stream>>>(S);
        // out = P V : per batch 8 m-tiles x 4 n-tiles -> gemm256
        gemm256<<<dim3(8, 4, 8), blk, 0, stream>>>(
            (const f16*)S, vT, nullptr, d_out, nullptr, nullptr, nullptr,
            2048, 4096, 2048, 1024, 2,
            (long)Nn_ * 4096, (long)Dd * Nn_, (long)Nn_ * Dd);
    } else {
        f16* xh  = wsh;
        f16* Wh  = wsh + 16777216;
        float* bqkv = (float*)(wsh + 19922944);
        f16* qh  = wsh + 19929088;
        f16* kh  = qh + 16777216;
        f16* vT  = kh + 16777216;
        float* S = (float*)(vT + 16777216);

        cvt_kernel<<<16384, 256, 0, stream>>>((const float4*)x, (f16x4*)xh, 4194304);
        cvt_kernel<<<1024, 256, 0, stream>>>((const float4*)Wq, (f16x4*)Wh, 262144);
        cvt_kernel<<<1024, 256, 0, stream>>>((const float4*)Wk, (f16x4*)(Wh + 1048576), 262144);
        cvt_kernel<<<1024, 256, 0, stream>>>((const float4*)Wv, (f16x4*)(Wh + 2097152), 262144);
        concat_bias<<<12, 256, 0, stream>>>(bq, bk, bv, bqkv);

        gemm256<<<dim3(64, 12, 1), blk, 0, stream>>>(
            xh, Wh, bqkv, nullptr, qh, kh, vT,
            1024, 1024, 1024, 0, 3, 0, 0, 0);

        for (int h = 0; h < 2; ++h) {
            const long b0 = 4L * h;
            gemm128<<<dim3(16, 8, 4), blk, 0, stream>>>(
                qh + b0 * Nn_ * Dd, kh + b0 * Nn_ * Dd, S,
                1024, 1024, 1024, 2048,
                (long)Nn_ * Dd, (long)Nn_ * Dd, (long)Nn_ * Nn_);
            softmax_rows<<<2048, 256, 0, stream>>>(S);
            gemm256<<<dim3(8, 4, 4), blk, 0, stream>>>(
                (const f16*)S, vT + b0 * Dd * Nn_, nullptr,
                (float*)d_out + b0 * Nn_ * Dd, nullptr, nullptr, nullptr,
                2048, 4096, 2048, 1024, 2,
                (long)Nn_ * 4096, (long)Dd * Nn_, (long)Nn_ * Dd);
        }
    }
}

// Round 4
// 452.023 us; speedup vs baseline: 1.0045x; 1.0045x over previous
//
#include <hip/hip_runtime.h>

// SelfAttentionLayer: B=8, N=2048, D=1024, fp32 in/out.
// R11: R9 base (all stages on the 256x256 4-phase kernel, best measured
// 434-435us) + vectorized qh/kh epilogue. R10's routing regressed (454us)
// and falsified the "S is slowest" attribution: the top dispatch is QKV
// (WRITE 165-184MB vs 96MB ideal = ~1.8x amplification from scalar 2-byte
// f16 stores). Fix: gather the 256x256 f16 output tile in LDS (exactly
// 64K f16 = sm, free after K-loop), chunk-XOR swizzled (chunk ^= row&7,
// write ~4-way / read 2-way conflict), then emit 16-B f16x8 coalesced
// stores (full sectors, no RMW).

typedef _Float16 f16;
typedef _Float16 f16x4 __attribute__((ext_vector_type(4)));
typedef _Float16 f16x8 __attribute__((ext_vector_type(8)));
typedef float f32x4 __attribute__((ext_vector_type(4)));

#define Nn_ 2048
#define Dd 1024

typedef const __attribute__((address_space(1))) void gvoid;
typedef __attribute__((address_space(3))) void lvoid;

__device__ __forceinline__ void glds16(const void* g, void* l) {
    __builtin_amdgcn_global_load_lds((gvoid*)g, (lvoid*)l, 16, 0, 0);
}
#define BARRIER()  asm volatile("s_barrier" ::: "memory")
#define LGKM0()    asm volatile("s_waitcnt lgkmcnt(0)" ::: "memory")
#define VM6()      asm volatile("s_waitcnt vmcnt(6)" ::: "memory")
#define VM0()      asm volatile("s_waitcnt vmcnt(0)" ::: "memory")
#define PRIO1()    __builtin_amdgcn_s_setprio(1)
#define PRIO0()    __builtin_amdgcn_s_setprio(0)
#define MFMA(a, b, c) __builtin_amdgcn_mfma_f32_16x16x32_f16((a), (b), (c), 0, 0, 0)

// ---------------- fp32 -> fp16 convert ----------------
__global__ void cvt_kernel(const float4* __restrict__ in, f16x4* __restrict__ out, int n4) {
    int i = blockIdx.x * 256 + threadIdx.x;
    if (i >= n4) return;
    float4 f = in[i];
    f16x4 h;
    h.x = (_Float16)f.x; h.y = (_Float16)f.y; h.z = (_Float16)f.z; h.w = (_Float16)f.w;
    out[i] = h;
}

// ---------------- bias concat: bqkv[3072] = [bq|bk|bv] ----------------
__global__ void concat_bias(const float* __restrict__ bq, const float* __restrict__ bk,
                            const float* __restrict__ bv, float* __restrict__ o) {
    int i = blockIdx.x * 256 + threadIdx.x;
    if (i >= 3072) return;
    o[i] = (i < 1024) ? bq[i] : (i < 2048 ? bk[i - 1024] : bv[i - 2048]);
}

// ---------------- BT GEMM, 256m x 256n tile, 512 threads --------------------
// C[m][n] = sum_k A[m][k] * Bm[n][k].
// mode 2: fp32 out row-major, no bias       (S-GEMM, PV->d_out)
// mode 3: merged QKV (N=3072, 12 n-tiles): by<4 -> qh, by<8 -> kh (both via
//         LDS gather + f16x8 stores), else vT[b][e][tok] via LDS transpose.
__global__ __launch_bounds__(512) void gemm_bt(
    const f16* __restrict__ A, const f16* __restrict__ Bm,
    const float* __restrict__ bias, void* __restrict__ Cout,
    f16* __restrict__ qh, f16* __restrict__ kh, f16* __restrict__ vT,
    int K, int lda, int ldb, int ldc, int mode,
    long aStride, long bStride, long cStride)
{
    __shared__ f16 sm[65536];   // 128 KiB: two 64 KiB stages
    const int tid = threadIdx.x;
    const int lane = tid & 63, wid = tid >> 6;
    const int quad = lane >> 4, l16 = lane & 15;
    const int wm = wid & 1;          // 2 m-positions (128 rows each)
    const int wn = wid >> 1;         // 4 n-positions (64 cols each)
    const long m0 = (long)blockIdx.x * 256, n0 = (long)blockIdx.y * 256;
    A += (long)blockIdx.z * aStride;
    Bm += (long)blockIdx.z * bStride;

    // staging: thread t covers row lr of each 64-row quarter; global source
    // chunk pre-swizzled so linear LDS dest yields chunk^(row&7) layout.
    const int lr = tid >> 3;
    const int sc8 = ((tid & 7) ^ (lr & 7)) * 8;
    const f16* pa = A + (m0 + lr) * (long)lda + sc8;
    const f16* pb = Bm + (n0 + lr) * (long)ldb + sc8;
    const long a64 = 64L * lda, b64 = 64L * ldb;

    const int aRow = (wm * 128 + l16) * 64;
    const int bRow = (wn * 64 + l16) * 64;
    const int co0 = (quad ^ (l16 & 7)) * 8;          // k-half 0
    const int co1 = ((quad + 4) ^ (l16 & 7)) * 8;    // k-half 1

    f32x4 acc[8][4];
#pragma unroll
    for (int i = 0; i < 8; i++)
#pragma unroll
        for (int j = 0; j < 4; j++) acc[i][j] = 0.0f;

    const int nk = K >> 6;

    // prologue: stage tiles 0 and 1 completely (16 loads), keep 6 in flight.
#pragma unroll
    for (int q = 0; q < 4; ++q) glds16(pa + q * a64, sm + tid * 8 + q * 4096);
#pragma unroll
    for (int q = 0; q < 4; ++q) glds16(pb + q * b64, sm + 16384 + tid * 8 + q * 4096);
    if (nk > 1) {
#pragma unroll
        for (int q = 0; q < 4; ++q)
            glds16(pa + q * a64 + 64, sm + 32768 + tid * 8 + q * 4096);
#pragma unroll
        for (int q = 0; q < 4; ++q)
            glds16(pb + q * b64 + 64, sm + 49152 + tid * 8 + q * 4096);
        VM6();
    } else {
        VM0();
    }
    BARRIER();

    f16x8 af0[2][4], af1[2][4], bf0[2][2], bf1[2][2];
    {
        const f16* As = sm;
        const f16* Bs = sm + 16384;
#pragma unroll
        for (int i = 0; i < 4; ++i) {
            af0[0][i] = *(const f16x8*)(As + aRow + i * 1024 + co0);
            af0[1][i] = *(const f16x8*)(As + aRow + i * 1024 + co1);
        }
#pragma unroll
        for (int j = 0; j < 2; ++j) {
            bf0[0][j] = *(const f16x8*)(Bs + bRow + j * 1024 + co0);
            bf0[1][j] = *(const f16x8*)(Bs + bRow + j * 1024 + co1);
        }
    }
    LGKM0();

    int bo = 0;
    for (int t = 0; t < nk; ++t) {
        const f16* As = sm + bo;
        const f16* Bs = As + 16384;
        const f16* An = sm + (bo ^ 32768);
        const f16* Bn = An + 16384;
        const long kt2 = (long)(t + 2) * 64;
        const bool st = (t + 2) < nk;

        // ---- ph0: MFMA q0 (af0,bf0) | read bf1 | stage A q0,q2 (t+2)
        BARRIER();
#pragma unroll
        for (int j = 0; j < 2; ++j) {
            bf1[0][j] = *(const f16x8*)(Bs + bRow + 2048 + j * 1024 + co0);
            bf1[1][j] = *(const f16x8*)(Bs + bRow + 2048 + j * 1024 + co1);
        }
        if (st) {
            glds16(pa + 0 * a64 + kt2, sm + bo + tid * 8);
            glds16(pa + 2 * a64 + kt2, sm + bo + tid * 8 + 2 * 4096);
        }
        PRIO1();
#pragma unroll
        for (int i = 0; i < 4; ++i)
#pragma unroll
            for (int j = 0; j < 2; ++j) {
                acc[i][j] = MFMA(af0[0][i], bf0[0][j], acc[i][j]);
                acc[i][j] = MFMA(af0[1][i], bf0[1][j], acc[i][j]);
            }
        PRIO0(); LGKM0();

        // ---- ph1: MFMA q1 (af0,bf1) | read af1 | stage B q0,q1 (t+2)
        BARRIER();
#pragma unroll
        for (int i = 0; i < 4; ++i) {
            af1[0][i] = *(const f16x8*)(As + aRow + 4096 + i * 1024 + co0);
            af1[1][i] = *(const f16x8*)(As + aRow + 4096 + i * 1024 + co1);
        }
        if (st) {
            glds16(pb + 0 * b64 + kt2, sm + bo + 16384 + tid * 8);
            glds16(pb + 1 * b64 + kt2, sm + bo + 16384 + tid * 8 + 4096);
        }
        PRIO1();
#pragma unroll
        for (int i = 0; i < 4; ++i)
#pragma unroll
            for (int j = 0; j < 2; ++j) {
                acc[i][2 + j] = MFMA(af0[0][i], bf1[0][j], acc[i][2 + j]);
                acc[i][2 + j] = MFMA(af0[1][i], bf1[1][j], acc[i][2 + j]);
            }
        PRIO0(); LGKM0();

        // ---- ph2: MFMA q2 (af1,bf0) | stage B q2,q3 (t+2) | vmcnt
        BARRIER();
        if (st) {
            glds16(pb + 2 * b64 + kt2, sm + bo + 16384 + tid * 8 + 2 * 4096);
            glds16(pb + 3 * b64 + kt2, sm + bo + 16384 + tid * 8 + 3 * 4096);
        }
        PRIO1();
#pragma unroll
        for (int i = 0; i < 4; ++i)
#pragma unroll
            for (int j = 0; j < 2; ++j) {
                acc[4 + i][j] = MFMA(af1[0][i], bf0[0][j], acc[4 + i][j]);
                acc[4 + i][j] = MFMA(af1[1][i], bf0[1][j], acc[4 + i][j]);
            }
        PRIO0();
        if (st) { VM6(); } else { VM0(); }

        // ---- ph3: MFMA q3 (af1,bf1) | read next af0,bf0 | stage A q1,q3
        BARRIER();
        if (t + 1 < nk) {
#pragma unroll
            for (int i = 0; i < 4; ++i) {
                af0[0][i] = *(const f16x8*)(An + aRow + i * 1024 + co0);
                af0[1][i] = *(const f16x8*)(An + aRow + i * 1024 + co1);
            }
#pragma unroll
            for (int j = 0; j < 2; ++j) {
                bf0[0][j] = *(const f16x8*)(Bn + bRow + j * 1024 + co0);
                bf0[1][j] = *(const f16x8*)(Bn + bRow + j * 1024 + co1);
            }
        }
        if (st) {
            glds16(pa + 1 * a64 + kt2, sm + bo + tid * 8 + 4096);
            glds16(pa + 3 * a64 + kt2, sm + bo + tid * 8 + 3 * 4096);
        }
        PRIO1();
#pragma unroll
        for (int i = 0; i < 4; ++i)
#pragma unroll
            for (int j = 0; j < 2; ++j) {
                acc[4 + i][2 + j] = MFMA(af1[0][i], bf1[0][j], acc[4 + i][2 + j]);
                acc[4 + i][2 + j] = MFMA(af1[1][i], bf1[1][j], acc[4 + i][2 + j]);
            }
        PRIO0(); LGKM0();
        bo ^= 32768;
    }

    if (mode == 2) {
        float* O = (float*)Cout + (long)blockIdx.z * cStride;
#pragma unroll
        for (int ct = 0; ct < 4; ct++) {
            long n = n0 + wn * 64 + ct * 16 + l16;
#pragma unroll
            for (int rt = 0; rt < 8; rt++) {
                long mb = m0 + wm * 128 + rt * 16 + quad * 4;
#pragma unroll
                for (int r = 0; r < 4; r++)
                    O[(mb + r) * ldc + n] = acc[rt][ct][r];
            }
        }
    } else {  // mode 3: merged QKV routing (n-tile = 256 wide)
        if (blockIdx.y < 8) {
            // qh/kh: gather full 256x256 f16 tile in LDS (chunk^row&7
            // swizzled), then coalesced f16x8 stores (full 16-B sectors).
            f16* O = (blockIdx.y < 4) ? qh : kh;
            const long nbase = (long)(n0 & 1023);
            __syncthreads();   // K-loop LDS fully dead (all waves)
#pragma unroll
            for (int ct = 0; ct < 4; ct++) {
                int col = wn * 64 + ct * 16 + l16;
                float bs = bias[n0 + col];
#pragma unroll
                for (int rt = 0; rt < 8; rt++) {
#pragma unroll
                    for (int r = 0; r < 4; r++) {
                        int row = wm * 128 + rt * 16 + quad * 4 + r;
                        int phys = (((col >> 3) ^ (row & 7)) << 3) | (col & 7);
                        sm[row * 256 + phys] = (f16)(acc[rt][ct][r] + bs);
                    }
                }
            }
            __syncthreads();
            const int rr = tid >> 5, cc = tid & 31;   // 16 rows x 32 chunks/pass
#pragma unroll
            for (int p = 0; p < 16; p++) {
                int row = rr + p * 16;
                int lch = cc ^ (row & 7);             // logical chunk
                f16x8 v = *(const f16x8*)(sm + row * 256 + cc * 8);
                *(f16x8*)(O + (m0 + row) * 1024 + nbase + lch * 8) = v;
            }
        } else {
            // V: transpose 256m x 256n tile through LDS in four 64-col groups;
            // write vT[b][e][tok] with contiguous rows.
            const long nb = n0 - 2048;
            const long vbase = (m0 >> 11) * (long)(Dd * Nn_) + (m0 & 2047);
#pragma unroll
            for (int g = 0; g < 4; ++g) {
                __syncthreads();
                if (wn == g) {
#pragma unroll
                    for (int ct = 0; ct < 4; ++ct) {
                        int cl = ct * 16 + l16;
                        float bs = bias[n0 + g * 64 + cl];
#pragma unroll
                        for (int rt = 0; rt < 8; rt++) {
                            int row = wm * 128 + rt * 16 + quad * 4;
#pragma unroll
                            for (int r = 0; r < 4; r++)
                                sm[cl * 264 + row + r] = (f16)(acc[rt][ct][r] + bs);
                        }
                    }
                }
                __syncthreads();
                const int rowi = tid >> 3, c = (tid & 7) * 32;
                f16* dst = vT + vbase + (nb + g * 64 + rowi) * (long)Nn_ + c;
                const f16* src = sm + rowi * 264 + c;
                *(f16x8*)(dst) = *(const f16x8*)(src);
                *(f16x8*)(dst + 8) = *(const f16x8*)(src + 8);
                *(f16x8*)(dst + 16) = *(const f16x8*)(src + 16);
                *(f16x8*)(dst + 24) = *(const f16x8*)(src + 24);
            }
        }
    }
}

// ---------------- row softmax, P fp16 written in-place over S fp32 --------
__global__ __launch_bounds__(256) void softmax_rows(float* __restrict__ S) {
    const int row = blockIdx.x * 4 + (threadIdx.x >> 6);
    const int lane = threadIdx.x & 63;
    float* Sr = S + (long)row * 2048;
    const float4* R4 = (const float4*)Sr;
    float4 t[8];
#pragma unroll
    for (int i = 0; i < 8; i++) t[i] = R4[lane + 64 * i];
    float mx = -1e30f;
#pragma unroll
    for (int i = 0; i < 8; i++)
        mx = fmaxf(mx, fmaxf(fmaxf(t[i].x, t[i].y), fmaxf(t[i].z, t[i].w)));
#pragma unroll
    for (int off = 1; off < 64; off <<= 1) mx = fmaxf(mx, __shfl_xor(mx, off, 64));
    float se = 0.0f;
#pragma unroll
    for (int i = 0; i < 8; i++) {
        t[i].x = __expf(t[i].x - mx); t[i].y = __expf(t[i].y - mx);
        t[i].z = __expf(t[i].z - mx); t[i].w = __expf(t[i].w - mx);
        se += t[i].x + t[i].y + t[i].z + t[i].w;
    }
#pragma unroll
    for (int off = 1; off < 64; off <<= 1) se += __shfl_xor(se, off, 64);
    const float li = 1.0f / se;
    f16x4* P4 = (f16x4*)Sr;
#pragma unroll
    for (int i = 0; i < 8; i++) {
        f16x4 h;
        h.x = (_Float16)(t[i].x * li); h.y = (_Float16)(t[i].y * li);
        h.z = (_Float16)(t[i].z * li); h.w = (_Float16)(t[i].w * li);
        P4[lane + 64 * i] = h;
    }
}

extern "C" void kernel_launch(void* const* d_in, const int* in_sizes, int n_in,
                              void* d_out, int out_size, void* d_ws, size_t ws_size,
                              hipStream_t stream) {
    const float* x  = (const float*)d_in[0];
    const float* Wq = (const float*)d_in[1];
    const float* bq = (const float*)d_in[2];
    const float* Wk = (const float*)d_in[3];
    const float* bk = (const float*)d_in[4];
    const float* Wv = (const float*)d_in[5];
    const float* bv = (const float*)d_in[6];

    f16* wsh = (f16*)d_ws;
    dim3 blk(512);
    const bool full = ws_size >= 234881024ULL;  // 224 MiB full-batch path

    if (full) {
        f16* qh  = wsh;
        f16* kh  = wsh + 16777216;
        f16* vT  = wsh + 33554432;
        float* S = (float*)(wsh + 50331648);        // 33554432 floats
        f16* xh  = wsh + 50331648;                  // overlaid in S (dead later)
        f16* Wh  = wsh + 67108864;
        float* bqkv = (float*)(wsh + 70254592);

        cvt_kernel<<<16384, 256, 0, stream>>>((const float4*)x, (f16x4*)xh, 4194304);
        cvt_kernel<<<1024, 256, 0, stream>>>((const float4*)Wq, (f16x4*)Wh, 262144);
        cvt_kernel<<<1024, 256, 0, stream>>>((const float4*)Wk, (f16x4*)(Wh + 1048576), 262144);
        cvt_kernel<<<1024, 256, 0, stream>>>((const float4*)Wv, (f16x4*)(Wh + 2097152), 262144);
        concat_bias<<<12, 256, 0, stream>>>(bq, bk, bv, bqkv);

        // QKV: M=16384 (64 m-tiles), N=3072 (12 n-tiles)
        gemm_bt<<<dim3(64, 12, 1), blk, 0, stream>>>(
            xh, Wh, bqkv, nullptr, qh, kh, vT,
            1024, 1024, 1024, 0, 3, 0, 0, 0);
        // S = Q K^T : per batch 8 m-tiles x 8 n-tiles
        gemm_bt<<<dim3(8, 8, 8), blk, 0, stream>>>(
            qh, kh, nullptr, S, nullptr, nullptr, nullptr,
            1024, 1024, 1024, 2048, 2,
            (long)Nn_ * Dd, (long)Nn_ * Dd, (long)Nn_ * Nn_);
        softmax_rows<<<4096, 256, 0, stream>>>(S);
        // out = P V : per batch 8 m-tiles x 4 n-tiles
        gemm_bt<<<dim3(8, 4, 8), blk, 0, stream>>>(
            (const f16*)S, vT, nullptr, d_out, nullptr, nullptr, nullptr,
            2048, 4096, 2048, 1024, 2,
            (long)Nn_ * 4096, (long)Dd * Nn_, (long)Nn_ * Dd);
    } else {
        f16* xh  = wsh;
        f16* Wh  = wsh + 16777216;
        float* bqkv = (float*)(wsh + 19922944);
        f16* qh  = wsh + 19929088;
        f16* kh  = qh + 16777216;
        f16* vT  = kh + 16777216;
        float* S = (float*)(vT + 16777216);

        cvt_kernel<<<16384, 256, 0, stream>>>((const float4*)x, (f16x4*)xh, 4194304);
        cvt_kernel<<<1024, 256, 0, stream>>>((const float4*)Wq, (f16x4*)Wh, 262144);
        cvt_kernel<<<1024, 256, 0, stream>>>((const float4*)Wk, (f16x4*)(Wh + 1048576), 262144);
        cvt_kernel<<<1024, 256, 0, stream>>>((const float4*)Wv, (f16x4*)(Wh + 2097152), 262144);
        concat_bias<<<12, 256, 0, stream>>>(bq, bk, bv, bqkv);

        gemm_bt<<<dim3(64, 12, 1), blk, 0, stream>>>(
            xh, Wh, bqkv, nullptr, qh, kh, vT,
            1024, 1024, 1024, 0, 3, 0, 0, 0);

        for (int h = 0; h < 2; ++h) {
            const long b0 = 4L * h;
            gemm_bt<<<dim3(8, 8, 4), blk, 0, stream>>>(
                qh + b0 * Nn_ * Dd, kh + b0 * Nn_ * Dd, nullptr, S,
                nullptr, nullptr, nullptr,
                1024, 1024, 1024, 2048, 2,
                (long)Nn_ * Dd, (long)Nn_ * Dd, (long)Nn_ * Nn_);
            softmax_rows<<<2048, 256, 0, stream>>>(S);
            gemm_bt<<<dim3(8, 4, 4), blk, 0, stream>>>(
                (const f16*)S, vT + b0 * Dd * Nn_, nullptr,
                (float*)d_out + b0 * Nn_ * Dd, nullptr, nullptr, nullptr,
                2048, 4096, 2048, 1024, 2,
                (long)Nn_ * 4096, (long)Dd * Nn_, (long)Nn_ * Dd);
        }
    }
}

// Round 5
// 417.152 us; speedup vs baseline: 1.0884x; 1.0836x over previous
//
#include <hip/hip_runtime.h>

// SelfAttentionLayer: B=8, N=2048, D=1024, fp32 in/out.
// R12: calibrated per-stage routing. Parts model (validated vs R7-R10 totals
// within ~1us): QKV: 128-kernel 127 vs 256-kernel 155; S: 128.5 vs 92;
// PV: 126 vs 116. Optimal: QKV->gemm128 (2 WG/CU hides short-nk pipeline +
// mode-3 epilogue stalls), S/PV->gemm256 (256^2 tile halves LDS traffic,
// clean mode-2 epilogue). gemm128 is R7-verbatim; gemm256 is R9-verbatim.

typedef _Float16 f16;
typedef _Float16 f16x4 __attribute__((ext_vector_type(4)));
typedef _Float16 f16x8 __attribute__((ext_vector_type(8)));
typedef float f32x4 __attribute__((ext_vector_type(4)));

#define Nn_ 2048
#define Dd 1024

typedef const __attribute__((address_space(1))) void gvoid;
typedef __attribute__((address_space(3))) void lvoid;

__device__ __forceinline__ void glds16(const void* g, void* l) {
    __builtin_amdgcn_global_load_lds((gvoid*)g, (lvoid*)l, 16, 0, 0);
}
#define BARRIER()  asm volatile("s_barrier" ::: "memory")
#define LGKM0()    asm volatile("s_waitcnt lgkmcnt(0)" ::: "memory")
#define VM6()      asm volatile("s_waitcnt vmcnt(6)" ::: "memory")
#define VM0()      asm volatile("s_waitcnt vmcnt(0)" ::: "memory")
#define PRIO1()    __builtin_amdgcn_s_setprio(1)
#define PRIO0()    __builtin_amdgcn_s_setprio(0)
#define MFMA(a, b, c) __builtin_amdgcn_mfma_f32_16x16x32_f16((a), (b), (c), 0, 0, 0)

__device__ __forceinline__ void bar_vm3() {
    asm volatile("s_waitcnt vmcnt(3)\n\ts_barrier" ::: "memory");
}
__device__ __forceinline__ void bar_vm0() {
    asm volatile("s_waitcnt vmcnt(0)\n\ts_barrier" ::: "memory");
}

// ---------------- fp32 -> fp16 convert ----------------
__global__ void cvt_kernel(const float4* __restrict__ in, f16x4* __restrict__ out, int n4) {
    int i = blockIdx.x * 256 + threadIdx.x;
    if (i >= n4) return;
    float4 f = in[i];
    f16x4 h;
    h.x = (_Float16)f.x; h.y = (_Float16)f.y; h.z = (_Float16)f.z; h.w = (_Float16)f.w;
    out[i] = h;
}

// ---------------- bias concat: bqkv[3072] = [bq|bk|bv] ----------------
__global__ void concat_bias(const float* __restrict__ bq, const float* __restrict__ bk,
                            const float* __restrict__ bv, float* __restrict__ o) {
    int i = blockIdx.x * 256 + threadIdx.x;
    if (i >= 3072) return;
    o[i] = (i < 1024) ? bq[i] : (i < 2048 ? bk[i - 1024] : bv[i - 2048]);
}

// ============ gemm128 (R7 verbatim): 128m x 256n, BK=32, 3-stage, 2 WG/CU ===
// mode 2: fp32 out row-major, no bias
// mode 3: merged QKV (N=3072, 12 n-tiles): by<4 -> qh, by<8 -> kh,
//         else vT[b][e][tok] via LDS transpose (coalesced stores).
__global__ __launch_bounds__(512) void gemm128(
    const f16* __restrict__ A, const f16* __restrict__ Bm,
    const float* __restrict__ bias, void* __restrict__ Cout,
    f16* __restrict__ qh, f16* __restrict__ kh, f16* __restrict__ vT,
    int K, int lda, int ldb, int ldc, int mode,
    long aStride, long bStride, long cStride)
{
    __shared__ f16 sm[36864];   // 72KB: three 24KB stages
    const int tid = threadIdx.x;
    const int lane = tid & 63, wid = tid >> 6;
    const int quad = lane >> 4, l16 = lane & 15;
    const int wm = (wid & 1) * 64;        // 2 m-positions
    const int wn = (wid >> 1) * 64;       // 4 n-positions
    const long m0 = (long)blockIdx.x * 128, n0 = (long)blockIdx.y * 256;
    const int bz = blockIdx.z;
    A += (long)bz * aStride;
    Bm += (long)bz * bStride;

    const int la = tid, lb0 = tid, lb1 = tid + 512;
    const long arow = m0 + (la >> 2);
    const long brow0 = n0 + (lb0 >> 2), brow1 = n0 + (lb1 >> 2);
    const int colA  = ((la & 3) ^ ((la >> 3) & 3)) * 8;
    const int colB0 = ((lb0 & 3) ^ ((lb0 >> 3) & 3)) * 8;
    const int colB1 = ((lb1 & 3) ^ ((lb1 >> 3) & 3)) * 8;

    const f16* pa  = A + arow * lda + colA;
    const f16* pb0 = Bm + brow0 * ldb + colB0;
    const f16* pb1 = Bm + brow1 * ldb + colB1;

    const int fo = (quad ^ ((l16 >> 1) & 3)) * 8;   // fragment chunk offset

    f32x4 acc[4][4];
#pragma unroll
    for (int i = 0; i < 4; i++)
#pragma unroll
        for (int j = 0; j < 4; j++) acc[i][j] = 0.0f;

    const int nk = K >> 5;
    // prologue: tiles 0,1 -> stages 0,1  (stage stride 12288 f16; Bs at +4096)
    glds16(pa, sm + la * 8);
    glds16(pb0, sm + 4096 + lb0 * 8);
    glds16(pb1, sm + 4096 + lb1 * 8);
    if (nk > 1) {
        glds16(pa + 32, sm + 12288 + la * 8);
        glds16(pb0 + 32, sm + 16384 + lb0 * 8);
        glds16(pb1 + 32, sm + 16384 + lb1 * 8);
    }

    int cur = 0;
    for (int it = 0; it < nk; ++it) {
        if (it + 1 < nk) bar_vm3(); else bar_vm0();
        if (it + 2 < nk) {
            f16* dst = sm + ((cur >= 1) ? (cur - 1) : 2) * 12288;  // (cur+2)%3
            const int ko = (it + 2) * 32;
            glds16(pa + ko, dst + la * 8);
            glds16(pb0 + ko, dst + 4096 + lb0 * 8);
            glds16(pb1 + ko, dst + 4096 + lb1 * 8);
        }
        const f16* As = sm + cur * 12288;
        const f16* Bs = As + 4096;
        f16x8 af[4], bf[4];
#pragma unroll
        for (int rt = 0; rt < 4; rt++)
            af[rt] = *(const f16x8*)(As + (wm + rt * 16 + l16) * 32 + fo);
#pragma unroll
        for (int ct = 0; ct < 4; ct++)
            bf[ct] = *(const f16x8*)(Bs + (wn + ct * 16 + l16) * 32 + fo);
#pragma unroll
        for (int rt = 0; rt < 4; rt++)
#pragma unroll
            for (int ct = 0; ct < 4; ct++)
                acc[rt][ct] = MFMA(af[rt], bf[ct], acc[rt][ct]);
        cur = (cur == 2) ? 0 : cur + 1;
    }

    if (mode == 2) {
        float* O = (float*)Cout + (long)bz * cStride;
#pragma unroll
        for (int ct = 0; ct < 4; ct++) {
            long n = n0 + wn + ct * 16 + l16;
#pragma unroll
            for (int rt = 0; rt < 4; rt++) {
                long mb = m0 + wm + rt * 16 + quad * 4;
#pragma unroll
                for (int r = 0; r < 4; r++)
                    O[(mb + r) * ldc + n] = acc[rt][ct][r];
            }
        }
    } else {  // mode 3: merged QKV routing (n-tile = 256 wide)
        if (blockIdx.y < 8) {
            f16* O = (blockIdx.y < 4) ? qh : kh;
#pragma unroll
            for (int ct = 0; ct < 4; ct++) {
                long n = n0 + wn + ct * 16 + l16;
                float bs = bias[n];
                long n1 = n & 1023;
#pragma unroll
                for (int rt = 0; rt < 4; rt++) {
                    long mb = m0 + wm + rt * 16 + quad * 4;
#pragma unroll
                    for (int r = 0; r < 4; r++)
                        O[(mb + r) * 1024 + n1] = (f16)(acc[rt][ct][r] + bs);
                }
            }
        } else {
            // V: transpose 128m x 256n tile through LDS in four 64-col groups;
            // write vT[b][e][tok] with contiguous rows.
            const long nb = n0 - 2048;
            const long vbase = (m0 >> 11) * (long)(Dd * Nn_) + (m0 & 2047);
#pragma unroll
            for (int g = 0; g < 4; ++g) {
                __syncthreads();
                if ((wid >> 1) == g) {   // 2 waves own this 64-col group
#pragma unroll
                    for (int ct = 0; ct < 4; ++ct) {
                        int cl = ct * 16 + l16;                 // 0..63
                        float bs = bias[n0 + g * 64 + cl];
#pragma unroll
                        for (int rt = 0; rt < 4; rt++) {
                            int row = wm + rt * 16 + quad * 4;  // + r, 0..127
#pragma unroll
                            for (int r = 0; r < 4; r++)
                                sm[cl * 136 + row + r] = (f16)(acc[rt][ct][r] + bs);
                        }
                    }
                }
                __syncthreads();
                const int rowi = tid >> 3, c = (tid & 7) * 16;
                f16* dst = vT + vbase + (nb + g * 64 + rowi) * (long)Nn_ + c;
                const f16* src = sm + rowi * 136 + c;
                *(f16x8*)(dst) = *(const f16x8*)(src);
                *(f16x8*)(dst + 8) = *(const f16x8*)(src + 8);
            }
        }
    }
}

// ============ gemm256 (R9 verbatim): 256m x 256n, BK=64, 4-phase, 1 WG/CU ===
// mode 2: fp32 out row-major, no bias (S-GEMM, PV->d_out). mode 3 unused here.
__global__ __launch_bounds__(512) void gemm256(
    const f16* __restrict__ A, const f16* __restrict__ Bm,
    const float* __restrict__ bias, void* __restrict__ Cout,
    f16* __restrict__ qh, f16* __restrict__ kh, f16* __restrict__ vT,
    int K, int lda, int ldb, int ldc, int mode,
    long aStride, long bStride, long cStride)
{
    __shared__ f16 sm[65536];   // 128 KiB: two 64 KiB stages
    const int tid = threadIdx.x;
    const int lane = tid & 63, wid = tid >> 6;
    const int quad = lane >> 4, l16 = lane & 15;
    const int wm = wid & 1;          // 2 m-positions (128 rows each)
    const int wn = wid >> 1;         // 4 n-positions (64 cols each)
    const long m0 = (long)blockIdx.x * 256, n0 = (long)blockIdx.y * 256;
    A += (long)blockIdx.z * aStride;
    Bm += (long)blockIdx.z * bStride;

    const int lr = tid >> 3;
    const int sc8 = ((tid & 7) ^ (lr & 7)) * 8;
    const f16* pa = A + (m0 + lr) * (long)lda + sc8;
    const f16* pb = Bm + (n0 + lr) * (long)ldb + sc8;
    const long a64 = 64L * lda, b64 = 64L * ldb;

    const int aRow = (wm * 128 + l16) * 64;
    const int bRow = (wn * 64 + l16) * 64;
    const int co0 = (quad ^ (l16 & 7)) * 8;          // k-half 0
    const int co1 = ((quad + 4) ^ (l16 & 7)) * 8;    // k-half 1

    f32x4 acc[8][4];
#pragma unroll
    for (int i = 0; i < 8; i++)
#pragma unroll
        for (int j = 0; j < 4; j++) acc[i][j] = 0.0f;

    const int nk = K >> 6;

#pragma unroll
    for (int q = 0; q < 4; ++q) glds16(pa + q * a64, sm + tid * 8 + q * 4096);
#pragma unroll
    for (int q = 0; q < 4; ++q) glds16(pb + q * b64, sm + 16384 + tid * 8 + q * 4096);
    if (nk > 1) {
#pragma unroll
        for (int q = 0; q < 4; ++q)
            glds16(pa + q * a64 + 64, sm + 32768 + tid * 8 + q * 4096);
#pragma unroll
        for (int q = 0; q < 4; ++q)
            glds16(pb + q * b64 + 64, sm + 49152 + tid * 8 + q * 4096);
        VM6();
    } else {
        VM0();
    }
    BARRIER();

    f16x8 af0[2][4], af1[2][4], bf0[2][2], bf1[2][2];
    {
        const f16* As = sm;
        const f16* Bs = sm + 16384;
#pragma unroll
        for (int i = 0; i < 4; ++i) {
            af0[0][i] = *(const f16x8*)(As + aRow + i * 1024 + co0);
            af0[1][i] = *(const f16x8*)(As + aRow + i * 1024 + co1);
        }
#pragma unroll
        for (int j = 0; j < 2; ++j) {
            bf0[0][j] = *(const f16x8*)(Bs + bRow + j * 1024 + co0);
            bf0[1][j] = *(const f16x8*)(Bs + bRow + j * 1024 + co1);
        }
    }
    LGKM0();

    int bo = 0;
    for (int t = 0; t < nk; ++t) {
        const f16* As = sm + bo;
        const f16* Bs = As + 16384;
        const f16* An = sm + (bo ^ 32768);
        const f16* Bn = An + 16384;
        const long kt2 = (long)(t + 2) * 64;
        const bool st = (t + 2) < nk;

        // ---- ph0: MFMA q0 (af0,bf0) | read bf1 | stage A q0,q2 (t+2)
        BARRIER();
#pragma unroll
        for (int j = 0; j < 2; ++j) {
            bf1[0][j] = *(const f16x8*)(Bs + bRow + 2048 + j * 1024 + co0);
            bf1[1][j] = *(const f16x8*)(Bs + bRow + 2048 + j * 1024 + co1);
        }
        if (st) {
            glds16(pa + 0 * a64 + kt2, sm + bo + tid * 8);
            glds16(pa + 2 * a64 + kt2, sm + bo + tid * 8 + 2 * 4096);
        }
        PRIO1();
#pragma unroll
        for (int i = 0; i < 4; ++i)
#pragma unroll
            for (int j = 0; j < 2; ++j) {
                acc[i][j] = MFMA(af0[0][i], bf0[0][j], acc[i][j]);
                acc[i][j] = MFMA(af0[1][i], bf0[1][j], acc[i][j]);
            }
        PRIO0(); LGKM0();

        // ---- ph1: MFMA q1 (af0,bf1) | read af1 | stage B q0,q1 (t+2)
        BARRIER();
#pragma unroll
        for (int i = 0; i < 4; ++i) {
            af1[0][i] = *(const f16x8*)(As + aRow + 4096 + i * 1024 + co0);
            af1[1][i] = *(const f16x8*)(As + aRow + 4096 + i * 1024 + co1);
        }
        if (st) {
            glds16(pb + 0 * b64 + kt2, sm + bo + 16384 + tid * 8);
            glds16(pb + 1 * b64 + kt2, sm + bo + 16384 + tid * 8 + 4096);
        }
        PRIO1();
#pragma unroll
        for (int i = 0; i < 4; ++i)
#pragma unroll
            for (int j = 0; j < 2; ++j) {
                acc[i][2 + j] = MFMA(af0[0][i], bf1[0][j], acc[i][2 + j]);
                acc[i][2 + j] = MFMA(af0[1][i], bf1[1][j], acc[i][2 + j]);
            }
        PRIO0(); LGKM0();

        // ---- ph2: MFMA q2 (af1,bf0) | stage B q2,q3 (t+2) | vmcnt
        BARRIER();
        if (st) {
            glds16(pb + 2 * b64 + kt2, sm + bo + 16384 + tid * 8 + 2 * 4096);
            glds16(pb + 3 * b64 + kt2, sm + bo + 16384 + tid * 8 + 3 * 4096);
        }
        PRIO1();
#pragma unroll
        for (int i = 0; i < 4; ++i)
#pragma unroll
            for (int j = 0; j < 2; ++j) {
                acc[4 + i][j] = MFMA(af1[0][i], bf0[0][j], acc[4 + i][j]);
                acc[4 + i][j] = MFMA(af1[1][i], bf0[1][j], acc[4 + i][j]);
            }
        PRIO0();
        if (st) { VM6(); } else { VM0(); }

        // ---- ph3: MFMA q3 (af1,bf1) | read next af0,bf0 | stage A q1,q3
        BARRIER();
        if (t + 1 < nk) {
#pragma unroll
            for (int i = 0; i < 4; ++i) {
                af0[0][i] = *(const f16x8*)(An + aRow + i * 1024 + co0);
                af0[1][i] = *(const f16x8*)(An + aRow + i * 1024 + co1);
            }
#pragma unroll
            for (int j = 0; j < 2; ++j) {
                bf0[0][j] = *(const f16x8*)(Bn + bRow + j * 1024 + co0);
                bf0[1][j] = *(const f16x8*)(Bn + bRow + j * 1024 + co1);
            }
        }
        if (st) {
            glds16(pa + 1 * a64 + kt2, sm + bo + tid * 8 + 4096);
            glds16(pa + 3 * a64 + kt2, sm + bo + tid * 8 + 3 * 4096);
        }
        PRIO1();
#pragma unroll
        for (int i = 0; i < 4; ++i)
#pragma unroll
            for (int j = 0; j < 2; ++j) {
                acc[4 + i][2 + j] = MFMA(af1[0][i], bf1[0][j], acc[4 + i][2 + j]);
                acc[4 + i][2 + j] = MFMA(af1[1][i], bf1[1][j], acc[4 + i][2 + j]);
            }
        PRIO0(); LGKM0();
        bo ^= 32768;
    }

    if (mode == 2) {
        float* O = (float*)Cout + (long)blockIdx.z * cStride;
#pragma unroll
        for (int ct = 0; ct < 4; ct++) {
            long n = n0 + wn * 64 + ct * 16 + l16;
#pragma unroll
            for (int rt = 0; rt < 8; rt++) {
                long mb = m0 + wm * 128 + rt * 16 + quad * 4;
#pragma unroll
                for (int r = 0; r < 4; r++)
                    O[(mb + r) * ldc + n] = acc[rt][ct][r];
            }
        }
    } else {  // mode 3 (unused in R12 routing; kept verbatim for codegen parity)
        if (blockIdx.y < 8) {
            f16* O = (blockIdx.y < 4) ? qh : kh;
#pragma unroll
            for (int ct = 0; ct < 4; ct++) {
                long n = n0 + wn * 64 + ct * 16 + l16;
                float bs = bias[n];
                long n1 = n & 1023;
#pragma unroll
                for (int rt = 0; rt < 8; rt++) {
                    long mb = m0 + wm * 128 + rt * 16 + quad * 4;
#pragma unroll
                    for (int r = 0; r < 4; r++)
                        O[(mb + r) * 1024 + n1] = (f16)(acc[rt][ct][r] + bs);
                }
            }
        } else {
            const long nb = n0 - 2048;
            const long vbase = (m0 >> 11) * (long)(Dd * Nn_) + (m0 & 2047);
#pragma unroll
            for (int g = 0; g < 4; ++g) {
                __syncthreads();
                if (wn == g) {
#pragma unroll
                    for (int ct = 0; ct < 4; ++ct) {
                        int cl = ct * 16 + l16;
                        float bs = bias[n0 + g * 64 + cl];
#pragma unroll
                        for (int rt = 0; rt < 8; rt++) {
                            int row = wm * 128 + rt * 16 + quad * 4;
#pragma unroll
                            for (int r = 0; r < 4; r++)
                                sm[cl * 264 + row + r] = (f16)(acc[rt][ct][r] + bs);
                        }
                    }
                }
                __syncthreads();
                const int rowi = tid >> 3, c = (tid & 7) * 32;
                f16* dst = vT + vbase + (nb + g * 64 + rowi) * (long)Nn_ + c;
                const f16* src = sm + rowi * 264 + c;
                *(f16x8*)(dst) = *(const f16x8*)(src);
                *(f16x8*)(dst + 8) = *(const f16x8*)(src + 8);
                *(f16x8*)(dst + 16) = *(const f16x8*)(src + 16);
                *(f16x8*)(dst + 24) = *(const f16x8*)(src + 24);
            }
        }
    }
}

// ---------------- row softmax, P fp16 written in-place over S fp32 --------
__global__ __launch_bounds__(256) void softmax_rows(float* __restrict__ S) {
    const int row = blockIdx.x * 4 + (threadIdx.x >> 6);
    const int lane = threadIdx.x & 63;
    float* Sr = S + (long)row * 2048;
    const float4* R4 = (const float4*)Sr;
    float4 t[8];
#pragma unroll
    for (int i = 0; i < 8; i++) t[i] = R4[lane + 64 * i];
    float mx = -1e30f;
#pragma unroll
    for (int i = 0; i < 8; i++)
        mx = fmaxf(mx, fmaxf(fmaxf(t[i].x, t[i].y), fmaxf(t[i].z, t[i].w)));
#pragma unroll
    for (int off = 1; off < 64; off <<= 1) mx = fmaxf(mx, __shfl_xor(mx, off, 64));
    float se = 0.0f;
#pragma unroll
    for (int i = 0; i < 8; i++) {
        t[i].x = __expf(t[i].x - mx); t[i].y = __expf(t[i].y - mx);
        t[i].z = __expf(t[i].z - mx); t[i].w = __expf(t[i].w - mx);
        se += t[i].x + t[i].y + t[i].z + t[i].w;
    }
#pragma unroll
    for (int off = 1; off < 64; off <<= 1) se += __shfl_xor(se, off, 64);
    const float li = 1.0f / se;
    f16x4* P4 = (f16x4*)Sr;
#pragma unroll
    for (int i = 0; i < 8; i++) {
        f16x4 h;
        h.x = (_Float16)(t[i].x * li); h.y = (_Float16)(t[i].y * li);
        h.z = (_Float16)(t[i].z * li); h.w = (_Float16)(t[i].w * li);
        P4[lane + 64 * i] = h;
    }
}

extern "C" void kernel_launch(void* const* d_in, const int* in_sizes, int n_in,
                              void* d_out, int out_size, void* d_ws, size_t ws_size,
                              hipStream_t stream) {
    const float* x  = (const float*)d_in[0];
    const float* Wq = (const float*)d_in[1];
    const float* bq = (const float*)d_in[2];
    const float* Wk = (const float*)d_in[3];
    const float* bk = (const float*)d_in[4];
    const float* Wv = (const float*)d_in[5];
    const float* bv = (const float*)d_in[6];

    f16* wsh = (f16*)d_ws;
    dim3 blk(512);
    const bool full = ws_size >= 234881024ULL;  // 224 MiB full-batch path

    if (full) {
        f16* qh  = wsh;
        f16* kh  = wsh + 16777216;
        f16* vT  = wsh + 33554432;
        float* S = (float*)(wsh + 50331648);        // 33554432 floats
        f16* xh  = wsh + 50331648;                  // overlaid in S (dead later)
        f16* Wh  = wsh + 67108864;
        float* bqkv = (float*)(wsh + 70254592);

        cvt_kernel<<<16384, 256, 0, stream>>>((const float4*)x, (f16x4*)xh, 4194304);
        cvt_kernel<<<1024, 256, 0, stream>>>((const float4*)Wq, (f16x4*)Wh, 262144);
        cvt_kernel<<<1024, 256, 0, stream>>>((const float4*)Wk, (f16x4*)(Wh + 1048576), 262144);
        cvt_kernel<<<1024, 256, 0, stream>>>((const float4*)Wv, (f16x4*)(Wh + 2097152), 262144);
        concat_bias<<<12, 256, 0, stream>>>(bq, bk, bv, bqkv);

        // QKV: M=16384 (128 m-tiles), N=3072 (12 n-tiles) -> gemm128 (2 WG/CU)
        gemm128<<<dim3(128, 12, 1), blk, 0, stream>>>(
            xh, Wh, bqkv, nullptr, qh, kh, vT,
            1024, 1024, 1024, 0, 3, 0, 0, 0);
        // S = Q K^T : per batch 8 m-tiles x 8 n-tiles -> gemm256
        gemm256<<<dim3(8, 8, 8), blk, 0, stream>>>(
            qh, kh, nullptr, S, nullptr, nullptr, nullptr,
            1024, 1024, 1024, 2048, 2,
            (long)Nn_ * Dd, (long)Nn_ * Dd, (long)Nn_ * Nn_);
        softmax_rows<<<4096, 256, 0, stream>>>(S);
        // out = P V : per batch 8 m-tiles x 4 n-tiles -> gemm256
        gemm256<<<dim3(8, 4, 8), blk, 0, stream>>>(
            (const f16*)S, vT, nullptr, d_out, nullptr, nullptr, nullptr,
            2048, 4096, 2048, 1024, 2,
            (long)Nn_ * 4096, (long)Dd * Nn_, (long)Nn_ * Dd);
    } else {
        f16* xh  = wsh;
        f16* Wh  = wsh + 16777216;
        float* bqkv = (float*)(wsh + 19922944);
        f16* qh  = wsh + 19929088;
        f16* kh  = qh + 16777216;
        f16* vT  = kh + 16777216;
        float* S = (float*)(vT + 16777216);

        cvt_kernel<<<16384, 256, 0, stream>>>((const float4*)x, (f16x4*)xh, 4194304);
        cvt_kernel<<<1024, 256, 0, stream>>>((const float4*)Wq, (f16x4*)Wh, 262144);
        cvt_kernel<<<1024, 256, 0, stream>>>((const float4*)Wk, (f16x4*)(Wh + 1048576), 262144);
        cvt_kernel<<<1024, 256, 0, stream>>>((const float4*)Wv, (f16x4*)(Wh + 2097152), 262144);
        concat_bias<<<12, 256, 0, stream>>>(bq, bk, bv, bqkv);

        gemm128<<<dim3(128, 12, 1), blk, 0, stream>>>(
            xh, Wh, bqkv, nullptr, qh, kh, vT,
            1024, 1024, 1024, 0, 3, 0, 0, 0);

        for (int h = 0; h < 2; ++h) {
            const long b0 = 4L * h;
            gemm256<<<dim3(8, 8, 4), blk, 0, stream>>>(
                qh + b0 * Nn_ * Dd, kh + b0 * Nn_ * Dd, nullptr, S,
                nullptr, nullptr, nullptr,
                1024, 1024, 1024, 2048, 2,
                (long)Nn_ * Dd, (long)Nn_ * Dd, (long)Nn_ * Nn_);
            softmax_rows<<<2048, 256, 0, stream>>>(S);
            gemm256<<<dim3(8, 4, 4), blk, 0, stream>>>(
                (const f16*)S, vT + b0 * Dd * Nn_, nullptr,
                (float*)d_out + b0 * Nn_ * Dd, nullptr, nullptr, nullptr,
                2048, 4096, 2048, 1024, 2,
                (long)Nn_ * 4096, (long)Dd * Nn_, (long)Nn_ * Dd);
        }
    }
}